// Round 8
// baseline (610.689 us; speedup 1.0000x reference)
//
#include <hip/hip_runtime.h>

#define NB 4
#define NN 10000
#define NE 320000
#define EPB 128
#define NPAIR (NE / EPB)          // 2500 tiles per batch
#define NT (NB * NPAIR)           // 10000 tiles
#define NPB 512                   // persistent blocks (2 per CU)

typedef unsigned int uint;
typedef unsigned short ushort;
typedef __attribute__((ext_vector_type(8))) short short8;
typedef __attribute__((ext_vector_type(4))) float f32x4;

// d_ws layout (bytes). All tables are A-fragments for the transposed scheme:
//   A-frag: laneDim row = mt*16 + lm ; elem j -> k = kt*32 + (j>>2)*16 + la*4 + (j&3)
#define WS_W1T 0        // 8 mt * 64 = 512 frags * 16B = 8KB   (K=6 padded to 32)
#define WS_W2T 8192     // 8 mt * 4 kt * 64 = 2048 frags = 32KB
#define WS_W3T 40960    // 32KB
#define WS_WVT 73728    // 12 mt * 64 = 768 frags = 12KB  (rows = o*3+c, K=18 pad 32)

static __device__ __forceinline__ ushort f2bf(float f) {
    uint u = __float_as_uint(f);
    u += 0x7fffu + ((u >> 16) & 1u);
    return (ushort)(u >> 16);
}
static __device__ __forceinline__ uint pack2(float a, float b) {
    return (uint)f2bf(a) | ((uint)f2bf(b) << 16);
}
static __device__ __forceinline__ uint cvtpk(float a, float b) {
    uint r;
    asm("v_cvt_pk_bf16_f32 %0, %1, %2" : "=v"(r) : "v"(a), "v"(b));
    return r;
}
static __device__ __forceinline__ short8 u4s8(uint4 v) {
    union { uint4 u; short8 s; } x; x.u = v; return x.s;
}
static __device__ __forceinline__ f32x4 MF(uint4 a, uint4 b, f32x4 c) {
    return __builtin_amdgcn_mfma_f32_16x16x32_bf16(u4s8(a), u4s8(b), c, 0, 0, 0);
}

// ---------------- prep: pack transposed weight fragment tables ----------------
__global__ void prep_kernel(const float* __restrict__ W1, const float* __restrict__ W2,
                            const float* __restrict__ W3, const float* __restrict__ Wv,
                            unsigned char* __restrict__ ws) {
    int tid = blockIdx.x * blockDim.x + threadIdx.x;
    if (tid < 4096) {
        const float* W = (tid < 2048) ? W2 : W3;
        uint4* dst = (uint4*)(ws + ((tid < 2048) ? WS_W2T : WS_W3T));
        int f = tid & 2047;                    // f = (mt*4 + kt)*64 + lane
        int lane = f & 63, kt = (f >> 6) & 3, mt = (f >> 8) & 7;
        int la = lane >> 4, lm = lane & 15;
        int n = mt * 16 + lm;
        uint w[4];
        #pragma unroll
        for (int jw = 0; jw < 4; ++jw) {
            int j0 = jw * 2, j1 = j0 + 1;
            int k0 = kt * 32 + (j0 >> 2) * 16 + la * 4 + (j0 & 3);
            int k1 = kt * 32 + (j1 >> 2) * 16 + la * 4 + (j1 & 3);
            w[jw] = pack2(W[n * 128 + k0], W[n * 128 + k1]);
        }
        dst[f] = make_uint4(w[0], w[1], w[2], w[3]);
    } else if (tid < 4608) {
        int f = tid - 4096;                    // f = mt*64 + lane, mt 0..7
        int lane = f & 63, mt = f >> 6;
        int la = lane >> 4, lm = lane & 15;
        int n = mt * 16 + lm;
        uint w[4];
        #pragma unroll
        for (int jw = 0; jw < 4; ++jw) {
            int j0 = jw * 2, j1 = j0 + 1;
            int k0 = (j0 >> 2) * 16 + la * 4 + (j0 & 3);
            int k1 = (j1 >> 2) * 16 + la * 4 + (j1 & 3);
            float f0 = (k0 < 6) ? W1[n * 6 + k0] : 0.f;
            float f1 = (k1 < 6) ? W1[n * 6 + k1] : 0.f;
            w[jw] = pack2(f0, f1);
        }
        ((uint4*)(ws + WS_W1T))[f] = make_uint4(w[0], w[1], w[2], w[3]);
    } else if (tid < 5376) {
        int f = tid - 4608;                    // f = mt*64 + lane, mt 0..11
        int lane = f & 63, mt = f >> 6;
        int la = lane >> 4, lm = lane & 15;
        int row = mt * 16 + lm;                // row = o*3 + c
        int o = row / 3, c = row - o * 3;
        uint w[4];
        #pragma unroll
        for (int jw = 0; jw < 4; ++jw) {
            float vv[2];
            #pragma unroll
            for (int dc = 0; dc < 2; ++dc) {
                int j = jw * 2 + dc;
                int k = (j >> 2) * 16 + la * 4 + (j & 3);
                int i = k / 3, cc = k - i * 3;
                vv[dc] = (k < 18 && cc == c) ? Wv[o * 6 + i] * (1.f / 3.f) : 0.f;
            }
            w[jw] = pack2(vv[0], vv[1]);
        }
        ((uint4*)(ws + WS_WVT))[f] = make_uint4(w[0], w[1], w[2], w[3]);
    }
}

// ---------------- main: persistent blocks; wv reloaded per tile; s_vec dbuf ----------------
// a_out path proven correct in round 7. v_out fixes: (a) wv frags reloaded from
// L1/L2 each iteration (no 48-VGPR persistent array), (b) s_vec double-buffered
// by iteration parity (no cross-iteration write-over-read hazard).
__global__ __launch_bounds__(256, 2)
void edge_kernel(const float* __restrict__ pos0, const float* __restrict__ pos1,
                 const int* __restrict__ src, const int* __restrict__ dstI,
                 const float* __restrict__ b1, const float* __restrict__ b2,
                 const float* __restrict__ b3,
                 const unsigned char* __restrict__ ws, float* __restrict__ out) {
    __shared__ uint4 s_W2[2048];           // 32KB
    __shared__ float s_pts[128][13];       // 6.5KB
    __shared__ float s_norm[6 * 128];      // 3KB
    __shared__ float s_vec[2][128][20];    // 20KB dbuf  -> total 62976B (<64KB)

    const int tid = threadIdx.x;
    const int lane = tid & 63;
    const int w = tid >> 6;
    const int lm = lane & 15;
    const int la = lane >> 4;
    const int ew0 = w * 32;             // wave's 32-edge slice
    const int el = ew0 + (lane & 31);
    const int side = lane >> 5;         // 0: src endpoint, 1: dst endpoint

    const uint4* W1T = (const uint4*)(ws + WS_W1T);
    const uint4* W2T = (const uint4*)(ws + WS_W2T);
    const uint4* W3T = (const uint4*)(ws + WS_W3T);
    const uint4* WVT = (const uint4*)(ws + WS_WVT);

    // stage W2 into LDS once
    #pragma unroll
    for (int it = 0; it < 8; ++it) s_W2[it * 256 + tid] = W2T[it * 256 + tid];

    // stationary register weights (W1 only; proven by a_out pass)
    uint4 w1f[8];
    #pragma unroll
    for (int mt = 0; mt < 8; ++mt) w1f[mt] = W1T[mt * 64 + lane];

    float* vout = out + (size_t)NB * NE * 128;
    const f32x4 zero4 = {0.f, 0.f, 0.f, 0.f};

    __syncthreads();

    // prologue: gather tile t0 into s_pts
    const int t0 = blockIdx.x;
    {
        const int b0 = t0 / NPAIR;
        const int e0p = (t0 - b0 * NPAIR) * EPB;
        const int node = side ? dstI[e0p + el] : src[e0p + el];
        const size_t pb = ((size_t)b0 * NN + node) * 3;
        s_pts[el][side * 3 + 0] = pos0[pb + 0];
        s_pts[el][side * 3 + 1] = pos0[pb + 1];
        s_pts[el][side * 3 + 2] = pos0[pb + 2];
        s_pts[el][6 + side * 3 + 0] = pos1[pb + 0];
        s_pts[el][6 + side * 3 + 1] = pos1[pb + 1];
        s_pts[el][6 + side * 3 + 2] = pos1[pb + 2];
    }

    int itc = 0;
    for (int t = t0; t < NT; t += NPB, ++itc) {
        const int b = t / NPAIR;
        const int e0 = (t - b * NPAIR) * EPB;
        const size_t eg0 = (size_t)b * NE + e0;
        float (*sv)[20] = s_vec[itc & 1];

        // --- early idx prefetch for next tile ---
        const int tn = t + NPB;
        const int tv = (tn < NT) ? tn : t;
        const int bn = tv / NPAIR;
        const int e0n = (tv - bn * NPAIR) * EPB;
        const int noden = side ? dstI[e0n + el] : src[e0n + el];

        // --- vecs + norms from s_pts (wave-local cross-lane, proven pattern) ---
        {
            float P[12];   // [p0s, p0d, p1s, p1d]
            #pragma unroll
            for (int i = 0; i < 12; ++i) P[i] = s_pts[el][i];
            if (side == 0) {
                const int va[4] = {1, 3, 2, 3}, vbx[4] = {0, 2, 0, 1};
                float v[4][3];
                #pragma unroll
                for (int i = 0; i < 4; ++i) {
                    #pragma unroll
                    for (int c = 0; c < 3; ++c) v[i][c] = P[va[i] * 3 + c] - P[vbx[i] * 3 + c];
                    s_norm[i * 128 + el] = sqrtf(v[i][0]*v[i][0] + v[i][1]*v[i][1] + v[i][2]*v[i][2]);
                }
                float4 t0v = {v[0][0], v[0][1], v[0][2], v[1][0]};
                float4 t1v = {v[1][1], v[1][2], v[2][0], v[2][1]};
                float4 t2v = {v[2][2], v[3][0], v[3][1], v[3][2]};
                *(float4*)&sv[el][0] = t0v;
                *(float4*)&sv[el][4] = t1v;
                *(float4*)&sv[el][8] = t2v;
            } else {
                float v4[3], v5[3];
                #pragma unroll
                for (int c = 0; c < 3; ++c) {
                    v4[c] = P[6 + c] - P[3 + c];   // p1s - p0d
                    v5[c] = P[9 + c] - P[0 + c];   // p1d - p0s
                }
                s_norm[4 * 128 + el] = sqrtf(v4[0]*v4[0] + v4[1]*v4[1] + v4[2]*v4[2]);
                s_norm[5 * 128 + el] = sqrtf(v5[0]*v5[0] + v5[1]*v5[1] + v5[2]*v5[2]);
                float4 tv4 = {v4[0], v4[1], v4[2], v5[0]};
                *(float4*)&sv[el][12] = tv4;
                float2 tv2 = {v5[1], v5[2]};
                *(float2*)&sv[el][16] = tv2;
            }
        }

        // --- v_out: wv frags reloaded (L1-hot), B-frags from sv, direct stores ---
        {
            uint4 vbv[2];
            #pragma unroll
            for (int nt = 0; nt < 2; ++nt) {
                const int e = ew0 + nt * 16 + lm;
                float4 q = *(const float4*)&sv[e][la * 4];
                uint c2 = 0;
                if (la == 0) c2 = cvtpk(sv[e][16], sv[e][17]);
                vbv[nt] = make_uint4(cvtpk(q.x, q.y), cvtpk(q.z, q.w), c2, 0u);
            }
            #pragma unroll
            for (int mt = 0; mt < 12; ++mt) {
                uint4 wvm = WVT[mt * 64 + lane];
                #pragma unroll
                for (int nt = 0; nt < 2; ++nt) {
                    f32x4 av = MF(wvm, vbv[nt], zero4);
                    const size_t e = eg0 + ew0 + nt * 16 + lm;
                    *(f32x4*)&vout[e * 192 + mt * 16 + la * 4] = av;
                }
            }
        }

        // --- pos prefetch for next tile -> s_pts ---
        {
            const size_t pbn = ((size_t)bn * NN + noden) * 3;
            float a0 = pos0[pbn], a1 = pos0[pbn + 1], a2 = pos0[pbn + 2];
            float c0 = pos1[pbn], c1 = pos1[pbn + 1], c2 = pos1[pbn + 2];
            s_pts[el][side * 3 + 0] = a0;
            s_pts[el][side * 3 + 1] = a1;
            s_pts[el][side * 3 + 2] = a2;
            s_pts[el][6 + side * 3 + 0] = c0;
            s_pts[el][6 + side * 3 + 1] = c1;
            s_pts[el][6 + side * 3 + 2] = c2;
        }

        // --- layer 1 (stationary reg weights) ---
        f32x4 acc[8][2];
        {
            uint4 vb1[2];
            #pragma unroll
            for (int nt = 0; nt < 2; ++nt) {
                const int e = ew0 + nt * 16 + lm;
                uint c0 = 0, c1 = 0;
                if (la == 0) {
                    c0 = cvtpk(s_norm[0 * 128 + e], s_norm[1 * 128 + e]);
                    c1 = cvtpk(s_norm[2 * 128 + e], s_norm[3 * 128 + e]);
                } else if (la == 1) {
                    c0 = cvtpk(s_norm[4 * 128 + e], s_norm[5 * 128 + e]);
                }
                vb1[nt] = make_uint4(c0, c1, 0u, 0u);
            }
            #pragma unroll
            for (int mt = 0; mt < 8; ++mt)
                #pragma unroll
                for (int nt = 0; nt < 2; ++nt)
                    acc[mt][nt] = MF(w1f[mt], vb1[nt], zero4);
        }
        uint4 vb[2][4];
        #pragma unroll
        for (int mt = 0; mt < 8; ++mt) {
            f32x4 bc = *(const f32x4*)&b1[mt * 16 + la * 4];
            #pragma unroll
            for (int nt = 0; nt < 2; ++nt)
                #pragma unroll
                for (int r = 0; r < 4; ++r) {
                    float x = acc[mt][nt][r] + bc[r];
                    acc[mt][nt][r] = fmaxf(x, 0.2f * x);
                }
        }
        #pragma unroll
        for (int nt = 0; nt < 2; ++nt)
            #pragma unroll
            for (int kt = 0; kt < 4; ++kt)
                vb[nt][kt] = make_uint4(
                    cvtpk(acc[2*kt][nt][0], acc[2*kt][nt][1]),
                    cvtpk(acc[2*kt][nt][2], acc[2*kt][nt][3]),
                    cvtpk(acc[2*kt+1][nt][0], acc[2*kt+1][nt][1]),
                    cvtpk(acc[2*kt+1][nt][2], acc[2*kt+1][nt][3]));

        // --- layer 2 (LDS weights) ---
        #pragma unroll
        for (int mt = 0; mt < 8; ++mt)
            #pragma unroll
            for (int nt = 0; nt < 2; ++nt) acc[mt][nt] = zero4;
        #pragma unroll
        for (int kt = 0; kt < 4; ++kt) {
            uint4 wf[8];
            #pragma unroll
            for (int mt = 0; mt < 8; ++mt) wf[mt] = s_W2[(mt * 4 + kt) * 64 + lane];
            #pragma unroll
            for (int mt = 0; mt < 8; ++mt)
                #pragma unroll
                for (int nt = 0; nt < 2; ++nt)
                    acc[mt][nt] = MF(wf[mt], vb[nt][kt], acc[mt][nt]);
        }
        #pragma unroll
        for (int mt = 0; mt < 8; ++mt) {
            f32x4 bc = *(const f32x4*)&b2[mt * 16 + la * 4];
            #pragma unroll
            for (int nt = 0; nt < 2; ++nt)
                #pragma unroll
                for (int r = 0; r < 4; ++r) {
                    float x = acc[mt][nt][r] + bc[r];
                    acc[mt][nt][r] = fmaxf(x, 0.2f * x);
                }
        }
        #pragma unroll
        for (int nt = 0; nt < 2; ++nt)
            #pragma unroll
            for (int kt = 0; kt < 4; ++kt)
                vb[nt][kt] = make_uint4(
                    cvtpk(acc[2*kt][nt][0], acc[2*kt][nt][1]),
                    cvtpk(acc[2*kt][nt][2], acc[2*kt][nt][3]),
                    cvtpk(acc[2*kt+1][nt][0], acc[2*kt+1][nt][1]),
                    cvtpk(acc[2*kt+1][nt][2], acc[2*kt+1][nt][3]));

        // --- layer 3 (W3 frags from L2) ---
        #pragma unroll
        for (int mt = 0; mt < 8; ++mt)
            #pragma unroll
            for (int nt = 0; nt < 2; ++nt) acc[mt][nt] = zero4;
        #pragma unroll
        for (int kt = 0; kt < 4; ++kt) {
            uint4 wf[8];
            #pragma unroll
            for (int mt = 0; mt < 8; ++mt) wf[mt] = W3T[(mt * 4 + kt) * 64 + lane];
            #pragma unroll
            for (int mt = 0; mt < 8; ++mt)
                #pragma unroll
                for (int nt = 0; nt < 2; ++nt)
                    acc[mt][nt] = MF(wf[mt], vb[nt][kt], acc[mt][nt]);
        }
        // bias3 + direct a_out stores
        #pragma unroll
        for (int mt = 0; mt < 8; ++mt) {
            f32x4 bc = *(const f32x4*)&b3[mt * 16 + la * 4];
            #pragma unroll
            for (int nt = 0; nt < 2; ++nt) {
                f32x4 v = acc[mt][nt] + bc;
                const size_t e = eg0 + ew0 + nt * 16 + lm;
                *(f32x4*)&out[e * 128 + mt * 16 + la * 4] = v;
            }
        }
    }
}

extern "C" void kernel_launch(void* const* d_in, const int* in_sizes, int n_in,
                              void* d_out, int out_size, void* d_ws, size_t ws_size,
                              hipStream_t stream) {
    const float* pos0 = (const float*)d_in[0];
    const float* pos1 = (const float*)d_in[1];
    const int* src = (const int*)d_in[2];
    const int* dstI = (const int*)d_in[3];
    const float* Wv = (const float*)d_in[4];
    const float* W1 = (const float*)d_in[5];
    const float* b1 = (const float*)d_in[6];
    const float* W2 = (const float*)d_in[7];
    const float* b2 = (const float*)d_in[8];
    const float* W3 = (const float*)d_in[9];
    const float* b3 = (const float*)d_in[10];
    unsigned char* ws = (unsigned char*)d_ws;
    float* out = (float*)d_out;

    prep_kernel<<<dim3(21), dim3(256), 0, stream>>>(W1, W2, W3, Wv, ws);
    edge_kernel<<<dim3(NPB), dim3(256), 0, stream>>>(pos0, pos1, src, dstI, b1, b2, b3, ws, out);
}

// Round 9
// 455.985 us; speedup vs baseline: 1.3393x; 1.3393x over previous
//
#include <hip/hip_runtime.h>

#define NB 4
#define NN 10000
#define NE 320000
#define EPB 128
#define NPAIR (NE / EPB)          // 2500 tiles per batch
#define NT (NB * NPAIR)           // 10000 tiles

typedef unsigned int uint;
typedef unsigned short ushort;
typedef __attribute__((ext_vector_type(8))) short short8;
typedef __attribute__((ext_vector_type(4))) float f32x4;

// d_ws layout (bytes). All tables are A-fragments for the transposed scheme:
//   A-frag: laneDim row = mt*16 + lm ; elem j -> k = kt*32 + (j>>2)*16 + la*4 + (j&3)
#define WS_W1T 0        // 8 mt * 64 = 512 frags * 16B = 8KB   (K=6 padded to 32)
#define WS_W2T 8192     // 8 mt * 4 kt * 64 = 2048 frags = 32KB
#define WS_W3T 40960    // 32KB
#define WS_WVT 73728    // 12 mt * 64 = 768 frags = 12KB  (rows = o*3+c, K=18 pad 32)

static __device__ __forceinline__ ushort f2bf(float f) {
    uint u = __float_as_uint(f);
    u += 0x7fffu + ((u >> 16) & 1u);
    return (ushort)(u >> 16);
}
static __device__ __forceinline__ uint pack2(float a, float b) {
    return (uint)f2bf(a) | ((uint)f2bf(b) << 16);
}
static __device__ __forceinline__ uint cvtpk(float a, float b) {
    uint r;
    asm("v_cvt_pk_bf16_f32 %0, %1, %2" : "=v"(r) : "v"(a), "v"(b));
    return r;
}
static __device__ __forceinline__ short8 u4s8(uint4 v) {
    union { uint4 u; short8 s; } x; x.u = v; return x.s;
}
static __device__ __forceinline__ f32x4 MF(uint4 a, uint4 b, f32x4 c) {
    return __builtin_amdgcn_mfma_f32_16x16x32_bf16(u4s8(a), u4s8(b), c, 0, 0, 0);
}

// ---------------- prep: pack transposed weight fragment tables ----------------
__global__ void prep_kernel(const float* __restrict__ W1, const float* __restrict__ W2,
                            const float* __restrict__ W3, const float* __restrict__ Wv,
                            unsigned char* __restrict__ ws) {
    int tid = blockIdx.x * blockDim.x + threadIdx.x;
    if (tid < 4096) {
        const float* W = (tid < 2048) ? W2 : W3;
        uint4* dst = (uint4*)(ws + ((tid < 2048) ? WS_W2T : WS_W3T));
        int f = tid & 2047;                    // f = (mt*4 + kt)*64 + lane
        int lane = f & 63, kt = (f >> 6) & 3, mt = (f >> 8) & 7;
        int la = lane >> 4, lm = lane & 15;
        int n = mt * 16 + lm;
        uint w[4];
        #pragma unroll
        for (int jw = 0; jw < 4; ++jw) {
            int j0 = jw * 2, j1 = j0 + 1;
            int k0 = kt * 32 + (j0 >> 2) * 16 + la * 4 + (j0 & 3);
            int k1 = kt * 32 + (j1 >> 2) * 16 + la * 4 + (j1 & 3);
            w[jw] = pack2(W[n * 128 + k0], W[n * 128 + k1]);
        }
        dst[f] = make_uint4(w[0], w[1], w[2], w[3]);
    } else if (tid < 4608) {
        int f = tid - 4096;                    // f = mt*64 + lane, mt 0..7
        int lane = f & 63, mt = f >> 6;
        int la = lane >> 4, lm = lane & 15;
        int n = mt * 16 + lm;
        uint w[4];
        #pragma unroll
        for (int jw = 0; jw < 4; ++jw) {
            int j0 = jw * 2, j1 = j0 + 1;
            int k0 = (j0 >> 2) * 16 + la * 4 + (j0 & 3);
            int k1 = (j1 >> 2) * 16 + la * 4 + (j1 & 3);
            float f0 = (k0 < 6) ? W1[n * 6 + k0] : 0.f;
            float f1 = (k1 < 6) ? W1[n * 6 + k1] : 0.f;
            w[jw] = pack2(f0, f1);
        }
        ((uint4*)(ws + WS_W1T))[f] = make_uint4(w[0], w[1], w[2], w[3]);
    } else if (tid < 5376) {
        int f = tid - 4608;                    // f = mt*64 + lane, mt 0..11
        int lane = f & 63, mt = f >> 6;
        int la = lane >> 4, lm = lane & 15;
        int row = mt * 16 + lm;                // row = o*3 + c
        int o = row / 3, c = row - o * 3;
        uint w[4];
        #pragma unroll
        for (int jw = 0; jw < 4; ++jw) {
            float vv[2];
            #pragma unroll
            for (int dc = 0; dc < 2; ++dc) {
                int j = jw * 2 + dc;
                int k = (j >> 2) * 16 + la * 4 + (j & 3);
                int i = k / 3, cc = k - i * 3;
                vv[dc] = (k < 18 && cc == c) ? Wv[o * 6 + i] * (1.f / 3.f) : 0.f;
            }
            w[jw] = pack2(vv[0], vv[1]);
        }
        ((uint4*)(ws + WS_WVT))[f] = make_uint4(w[0], w[1], w[2], w[3]);
    }
}

// ---------------- kernel A: v_out streamer (983 MB; homogeneous store stream) ----------------
__global__ __launch_bounds__(256, 4)
void vout_kernel(const float* __restrict__ pos0, const float* __restrict__ pos1,
                 const int* __restrict__ src, const int* __restrict__ dstI,
                 const unsigned char* __restrict__ ws, float* __restrict__ out) {
    __shared__ float s_pts[128][13];    // 6.5KB
    __shared__ float s_vec[128][20];    // 10.25KB

    const int tid = threadIdx.x;
    const int lane = tid & 63;
    const int w = tid >> 6;
    const int lm = lane & 15;
    const int la = lane >> 4;
    const int ew0 = w * 32;
    const int el = ew0 + (lane & 31);
    const int side = lane >> 5;

    const int t = blockIdx.x;
    const int b = t / NPAIR;
    const int e0 = (t - b * NPAIR) * EPB;
    const size_t eg0 = (size_t)b * NE + e0;

    // gather (wave-local slice)
    {
        const int node = side ? dstI[e0 + el] : src[e0 + el];
        const size_t pb = ((size_t)b * NN + node) * 3;
        s_pts[el][side * 3 + 0] = pos0[pb + 0];
        s_pts[el][side * 3 + 1] = pos0[pb + 1];
        s_pts[el][side * 3 + 2] = pos0[pb + 2];
        s_pts[el][6 + side * 3 + 0] = pos1[pb + 0];
        s_pts[el][6 + side * 3 + 1] = pos1[pb + 1];
        s_pts[el][6 + side * 3 + 2] = pos1[pb + 2];
    }
    // vecs (wave-local cross-lane; DS wave-ordered)
    {
        float P[12];
        #pragma unroll
        for (int i = 0; i < 12; ++i) P[i] = s_pts[el][i];
        if (side == 0) {
            const int va[4] = {1, 3, 2, 3}, vbx[4] = {0, 2, 0, 1};
            float v[4][3];
            #pragma unroll
            for (int i = 0; i < 4; ++i)
                #pragma unroll
                for (int c = 0; c < 3; ++c) v[i][c] = P[va[i] * 3 + c] - P[vbx[i] * 3 + c];
            float4 t0v = {v[0][0], v[0][1], v[0][2], v[1][0]};
            float4 t1v = {v[1][1], v[1][2], v[2][0], v[2][1]};
            float4 t2v = {v[2][2], v[3][0], v[3][1], v[3][2]};
            *(float4*)&s_vec[el][0] = t0v;
            *(float4*)&s_vec[el][4] = t1v;
            *(float4*)&s_vec[el][8] = t2v;
        } else {
            float v4[3], v5[3];
            #pragma unroll
            for (int c = 0; c < 3; ++c) {
                v4[c] = P[6 + c] - P[3 + c];   // p1s - p0d
                v5[c] = P[9 + c] - P[0 + c];   // p1d - p0s
            }
            float4 tv4 = {v4[0], v4[1], v4[2], v5[0]};
            *(float4*)&s_vec[el][12] = tv4;
            float2 tv2 = {v5[1], v5[2]};
            *(float2*)&s_vec[el][16] = tv2;
        }
    }
    // v_out: 24 MFMA + direct stores
    {
        uint4 vbv[2];
        #pragma unroll
        for (int nt = 0; nt < 2; ++nt) {
            const int e = ew0 + nt * 16 + lm;
            float4 q = *(const float4*)&s_vec[e][la * 4];
            uint c2 = 0;
            if (la == 0) c2 = cvtpk(s_vec[e][16], s_vec[e][17]);
            vbv[nt] = make_uint4(cvtpk(q.x, q.y), cvtpk(q.z, q.w), c2, 0u);
        }
        const uint4* WVT = (const uint4*)(ws + WS_WVT);
        uint4 wv[12];
        #pragma unroll
        for (int mt = 0; mt < 12; ++mt) wv[mt] = WVT[mt * 64 + lane];
        float* vout = out + (size_t)NB * NE * 128;
        const f32x4 zero4 = {0.f, 0.f, 0.f, 0.f};
        #pragma unroll
        for (int mt = 0; mt < 12; ++mt)
            #pragma unroll
            for (int nt = 0; nt < 2; ++nt) {
                f32x4 av = MF(wv[mt], vbv[nt], zero4);
                const size_t e = eg0 + ew0 + nt * 16 + lm;
                *(f32x4*)&vout[e * 192 + mt * 16 + la * 4] = av;
            }
    }
}

// ---------------- kernel B: MLP -> a_out (655 MB; weights from L2, zero barriers) ----------------
__global__ __launch_bounds__(256, 3)
void aout_kernel(const float* __restrict__ pos0, const float* __restrict__ pos1,
                 const int* __restrict__ src, const int* __restrict__ dstI,
                 const float* __restrict__ b1, const float* __restrict__ b2,
                 const float* __restrict__ b3,
                 const unsigned char* __restrict__ ws, float* __restrict__ out) {
    __shared__ float s_pts[128][13];    // 6.5KB
    __shared__ float s_norm[6 * 128];   // 3KB

    const int tid = threadIdx.x;
    const int lane = tid & 63;
    const int w = tid >> 6;
    const int lm = lane & 15;
    const int la = lane >> 4;
    const int ew0 = w * 32;
    const int el = ew0 + (lane & 31);
    const int side = lane >> 5;

    const int t = blockIdx.x;
    const int b = t / NPAIR;
    const int e0 = (t - b * NPAIR) * EPB;
    const size_t eg0 = (size_t)b * NE + e0;

    const uint4* W1T = (const uint4*)(ws + WS_W1T);
    const uint4* W2T = (const uint4*)(ws + WS_W2T);
    const uint4* W3T = (const uint4*)(ws + WS_W3T);
    const f32x4 zero4 = {0.f, 0.f, 0.f, 0.f};

    // gather (wave-local slice)
    {
        const int node = side ? dstI[e0 + el] : src[e0 + el];
        const size_t pb = ((size_t)b * NN + node) * 3;
        s_pts[el][side * 3 + 0] = pos0[pb + 0];
        s_pts[el][side * 3 + 1] = pos0[pb + 1];
        s_pts[el][side * 3 + 2] = pos0[pb + 2];
        s_pts[el][6 + side * 3 + 0] = pos1[pb + 0];
        s_pts[el][6 + side * 3 + 1] = pos1[pb + 1];
        s_pts[el][6 + side * 3 + 2] = pos1[pb + 2];
    }
    // norms (wave-local)
    {
        float P[12];
        #pragma unroll
        for (int i = 0; i < 12; ++i) P[i] = s_pts[el][i];
        if (side == 0) {
            const int va[4] = {1, 3, 2, 3}, vbx[4] = {0, 2, 0, 1};
            #pragma unroll
            for (int i = 0; i < 4; ++i) {
                float x = P[va[i] * 3 + 0] - P[vbx[i] * 3 + 0];
                float y = P[va[i] * 3 + 1] - P[vbx[i] * 3 + 1];
                float z = P[va[i] * 3 + 2] - P[vbx[i] * 3 + 2];
                s_norm[i * 128 + el] = sqrtf(x * x + y * y + z * z);
            }
        } else {
            float x4 = P[6] - P[3], y4 = P[7] - P[4], z4 = P[8] - P[5];
            float x5 = P[9] - P[0], y5 = P[10] - P[1], z5 = P[11] - P[2];
            s_norm[4 * 128 + el] = sqrtf(x4 * x4 + y4 * y4 + z4 * z4);
            s_norm[5 * 128 + el] = sqrtf(x5 * x5 + y5 * y5 + z5 * z5);
        }
    }

    // --- layer 1 ---
    f32x4 acc[8][2];
    {
        uint4 vb1[2];
        #pragma unroll
        for (int nt = 0; nt < 2; ++nt) {
            const int e = ew0 + nt * 16 + lm;
            uint c0 = 0, c1 = 0;
            if (la == 0) {
                c0 = cvtpk(s_norm[0 * 128 + e], s_norm[1 * 128 + e]);
                c1 = cvtpk(s_norm[2 * 128 + e], s_norm[3 * 128 + e]);
            } else if (la == 1) {
                c0 = cvtpk(s_norm[4 * 128 + e], s_norm[5 * 128 + e]);
            }
            vb1[nt] = make_uint4(c0, c1, 0u, 0u);
        }
        #pragma unroll
        for (int mt = 0; mt < 8; ++mt) {
            uint4 w1m = W1T[mt * 64 + lane];
            #pragma unroll
            for (int nt = 0; nt < 2; ++nt)
                acc[mt][nt] = MF(w1m, vb1[nt], zero4);
        }
    }
    uint4 vb[2][4];
    #pragma unroll
    for (int mt = 0; mt < 8; ++mt) {
        f32x4 bc = *(const f32x4*)&b1[mt * 16 + la * 4];
        #pragma unroll
        for (int nt = 0; nt < 2; ++nt)
            #pragma unroll
            for (int r = 0; r < 4; ++r) {
                float x = acc[mt][nt][r] + bc[r];
                acc[mt][nt][r] = fmaxf(x, 0.2f * x);
            }
    }
    #pragma unroll
    for (int nt = 0; nt < 2; ++nt)
        #pragma unroll
        for (int kt = 0; kt < 4; ++kt)
            vb[nt][kt] = make_uint4(
                cvtpk(acc[2*kt][nt][0], acc[2*kt][nt][1]),
                cvtpk(acc[2*kt][nt][2], acc[2*kt][nt][3]),
                cvtpk(acc[2*kt+1][nt][0], acc[2*kt+1][nt][1]),
                cvtpk(acc[2*kt+1][nt][2], acc[2*kt+1][nt][3]));

    // --- layer 2 (W2 from L2) ---
    #pragma unroll
    for (int mt = 0; mt < 8; ++mt)
        #pragma unroll
        for (int nt = 0; nt < 2; ++nt) acc[mt][nt] = zero4;
    #pragma unroll
    for (int kt = 0; kt < 4; ++kt) {
        uint4 wf[8];
        #pragma unroll
        for (int mt = 0; mt < 8; ++mt) wf[mt] = W2T[(mt * 4 + kt) * 64 + lane];
        #pragma unroll
        for (int mt = 0; mt < 8; ++mt)
            #pragma unroll
            for (int nt = 0; nt < 2; ++nt)
                acc[mt][nt] = MF(wf[mt], vb[nt][kt], acc[mt][nt]);
    }
    #pragma unroll
    for (int mt = 0; mt < 8; ++mt) {
        f32x4 bc = *(const f32x4*)&b2[mt * 16 + la * 4];
        #pragma unroll
        for (int nt = 0; nt < 2; ++nt)
            #pragma unroll
            for (int r = 0; r < 4; ++r) {
                float x = acc[mt][nt][r] + bc[r];
                acc[mt][nt][r] = fmaxf(x, 0.2f * x);
            }
    }
    #pragma unroll
    for (int nt = 0; nt < 2; ++nt)
        #pragma unroll
        for (int kt = 0; kt < 4; ++kt)
            vb[nt][kt] = make_uint4(
                cvtpk(acc[2*kt][nt][0], acc[2*kt][nt][1]),
                cvtpk(acc[2*kt][nt][2], acc[2*kt][nt][3]),
                cvtpk(acc[2*kt+1][nt][0], acc[2*kt+1][nt][1]),
                cvtpk(acc[2*kt+1][nt][2], acc[2*kt+1][nt][3]));

    // --- layer 3 (W3 from L2) + a_out stores ---
    #pragma unroll
    for (int mt = 0; mt < 8; ++mt)
        #pragma unroll
        for (int nt = 0; nt < 2; ++nt) acc[mt][nt] = zero4;
    #pragma unroll
    for (int kt = 0; kt < 4; ++kt) {
        uint4 wf[8];
        #pragma unroll
        for (int mt = 0; mt < 8; ++mt) wf[mt] = W3T[(mt * 4 + kt) * 64 + lane];
        #pragma unroll
        for (int mt = 0; mt < 8; ++mt)
            #pragma unroll
            for (int nt = 0; nt < 2; ++nt)
                acc[mt][nt] = MF(wf[mt], vb[nt][kt], acc[mt][nt]);
    }
    #pragma unroll
    for (int mt = 0; mt < 8; ++mt) {
        f32x4 bc = *(const f32x4*)&b3[mt * 16 + la * 4];
        #pragma unroll
        for (int nt = 0; nt < 2; ++nt) {
            f32x4 v = acc[mt][nt] + bc;
            const size_t e = eg0 + ew0 + nt * 16 + lm;
            *(f32x4*)&out[e * 128 + mt * 16 + la * 4] = v;
        }
    }
}

extern "C" void kernel_launch(void* const* d_in, const int* in_sizes, int n_in,
                              void* d_out, int out_size, void* d_ws, size_t ws_size,
                              hipStream_t stream) {
    const float* pos0 = (const float*)d_in[0];
    const float* pos1 = (const float*)d_in[1];
    const int* src = (const int*)d_in[2];
    const int* dstI = (const int*)d_in[3];
    const float* Wv = (const float*)d_in[4];
    const float* W1 = (const float*)d_in[5];
    const float* b1 = (const float*)d_in[6];
    const float* W2 = (const float*)d_in[7];
    const float* b2 = (const float*)d_in[8];
    const float* W3 = (const float*)d_in[9];
    const float* b3 = (const float*)d_in[10];
    unsigned char* ws = (unsigned char*)d_ws;
    float* out = (float*)d_out;

    prep_kernel<<<dim3(21), dim3(256), 0, stream>>>(W1, W2, W3, Wv, ws);
    vout_kernel<<<dim3(NT), dim3(256), 0, stream>>>(pos0, pos1, src, dstI, ws, out);
    aout_kernel<<<dim3(NT), dim3(256), 0, stream>>>(pos0, pos1, src, dstI, b1, b2, b3, ws, out);
}